// Round 1
// baseline (542.475 us; speedup 1.0000x reference)
//
#include <hip/hip_runtime.h>
#include <hip/hip_bf16.h>

typedef __bf16 bf16x8 __attribute__((ext_vector_type(8)));
typedef __bf16 bf16x4 __attribute__((ext_vector_type(4)));
typedef float  f32x4  __attribute__((ext_vector_type(4)));

#define B_ 4
#define T_ 2048
#define H_ 16
#define D_ 64
#define C_ 1024
#define M_ 8192                    // B*T
#define NE_ ((size_t)M_ * C_)      // elems per (M,C) tensor

// ---------------------------------------------------------------------------
// Probe: flag=1 if inputs are fp32, flag=0 if bf16.
// ---------------------------------------------------------------------------
__global__ void probe_dtype(const unsigned short* __restrict__ x,
                            int* __restrict__ flag)
{
  __shared__ float red[256];
  float m = 0.0f;
  for (int i = threadIdx.x; i < 4096; i += 256) {
    unsigned int u = ((unsigned int)x[i]) << 16;
    float v = fabsf(__uint_as_float(u));
    if (!(v <= 1e30f)) v = 1e31f;
    m = fmaxf(m, v);
  }
  red[threadIdx.x] = m;
  __syncthreads();
  for (int s = 128; s > 0; s >>= 1) {
    if (threadIdx.x < s) red[threadIdx.x] = fmaxf(red[threadIdx.x], red[threadIdx.x + s]);
    __syncthreads();
  }
  if (threadIdx.x == 0) *flag = (red[0] > 100.0f) ? 1 : 0;
}

__device__ __forceinline__ float load1_adapt(const void* p, size_t idx, int f)
{
  if (f) return ((const float*)p)[idx];
  return __bfloat162float(((const __hip_bfloat16*)p)[idx]);
}

// ---------------------------------------------------------------------------
// Convert a tensor to bf16 (fp32 src if flag, else plain bf16 copy).
// ---------------------------------------------------------------------------
__global__ __launch_bounds__(256) void cvt_bf16(
    const int* __restrict__ flagp, const void* __restrict__ src,
    __bf16* __restrict__ dst, int n)
{
  const int f = *flagp;
  for (size_t i = ((size_t)blockIdx.x * 256 + threadIdx.x) * 8; i < (size_t)n;
       i += (size_t)gridDim.x * 2048) {
    bf16x8 r;
    if (f) {
      const float* pf = (const float*)src + i;
      float4 a = *(const float4*)pf;
      float4 b = *(const float4*)(pf + 4);
      r[0] = (__bf16)a.x; r[1] = (__bf16)a.y; r[2] = (__bf16)a.z; r[3] = (__bf16)a.w;
      r[4] = (__bf16)b.x; r[5] = (__bf16)b.y; r[6] = (__bf16)b.z; r[7] = (__bf16)b.w;
    } else {
      r = *(const bf16x8*)((const __bf16*)src + i);
    }
    *(bf16x8*)(dst + i) = r;
  }
}

// ---------------------------------------------------------------------------
// async 16B global -> LDS copy (gfx950 global_load_lds dwordx4)
// ---------------------------------------------------------------------------
__device__ __forceinline__ void g2lds16(const __bf16* g, __bf16* l)
{
  __builtin_amdgcn_global_load_lds(
      (const __attribute__((address_space(1))) void*)g,
      (__attribute__((address_space(3))) void*)l, 16, 0, 0);
}

// ---------------------------------------------------------------------------
// m97-style GEMM: C = A * Bm^T. A: MxK bf16, Bm: NxK bf16. 128x128 tile,
// BK=64, 4 waves (2x2), global_load_lds width-16 staging (unpadded LDS —
// required by the wave-uniform-base + lane*16 constraint).
// XCD-aware swizzle: nwg=512 divisible by 8; XCD j owns one 128-col B-panel
// (256 KB, L2-resident) and streams A tiles sequentially.
// Output: bf16, or fp32 when (adaptive && *flagp).
// ---------------------------------------------------------------------------
__global__ __launch_bounds__(256) void gemm128(
    const __bf16* __restrict__ A, const __bf16* __restrict__ Bm,
    void* __restrict__ C, int M, int N, int K,
    const int* __restrict__ flagp, int adaptive)
{
  __shared__ __bf16 As[128][64];
  __shared__ __bf16 Bs[128][64];

  const int tid  = threadIdx.x;
  const int wv   = tid >> 6;
  const int lane = tid & 63;
  const int n16  = lane & 15;
  const int quad = lane >> 4;
  const int wm = (wv & 1) * 64, wn = (wv >> 1) * 64;

  // XCD-aware bijective swizzle (nwg % 8 == 0 for this launch: 64x8=512)
  const int nwgx = gridDim.x;
  const int id   = blockIdx.y * nwgx + blockIdx.x;
  const int cpx  = (nwgx * gridDim.y) >> 3;
  const int swz  = (id & 7) * cpx + (id >> 3);
  const int m0 = (swz % nwgx) * 128, n0 = (swz / nwgx) * 128;

  f32x4 acc[4][4];
#pragma unroll
  for (int i = 0; i < 4; i++)
#pragma unroll
    for (int j = 0; j < 4; j++) acc[i][j] = (f32x4){0.f, 0.f, 0.f, 0.f};

  const int trow = tid >> 3;          // 0..31
  const int tcol = (tid & 7) * 8;     // 0..56

  for (int k0 = 0; k0 < K; k0 += 64) {
#pragma unroll
    for (int p = 0; p < 4; p++) {
      g2lds16(A  + (size_t)(m0 + trow + p * 32) * K + k0 + tcol,
              &As[trow + p * 32][tcol]);
      g2lds16(Bm + (size_t)(n0 + trow + p * 32) * K + k0 + tcol,
              &Bs[trow + p * 32][tcol]);
    }
    __syncthreads();   // drains vmcnt(0): LDS is valid

#pragma unroll
    for (int kk = 0; kk < 2; kk++) {
      bf16x8 af[4], bf[4];
#pragma unroll
      for (int i = 0; i < 4; i++) {
        af[i] = *(const bf16x8*)&As[wm + i * 16 + n16][kk * 32 + quad * 8];
        bf[i] = *(const bf16x8*)&Bs[wn + i * 16 + n16][kk * 32 + quad * 8];
      }
#pragma unroll
      for (int i = 0; i < 4; i++)
#pragma unroll
        for (int j = 0; j < 4; j++)
          acc[i][j] = __builtin_amdgcn_mfma_f32_16x16x32_bf16(af[i], bf[j],
                                                              acc[i][j], 0, 0, 0);
    }
    __syncthreads();
  }

  const int f = adaptive ? *flagp : 0;
  const int rb = quad * 4;
#pragma unroll
  for (int i = 0; i < 4; i++)
#pragma unroll
    for (int j = 0; j < 4; j++)
#pragma unroll
      for (int r = 0; r < 4; r++) {
        const size_t idx = (size_t)(m0 + wm + i * 16 + rb + r) * N
                           + n0 + wn + j * 16 + n16;
        if (f) ((float*)C)[idx] = acc[i][j][r];
        else   ((__bf16*)C)[idx] = (__bf16)acc[i][j][r];
      }
}

// ---------------------------------------------------------------------------
// Fused rmsnorm+RoPE on q,k (bf16, in place) + v mix (bf16 in place, v1 raw).
// ---------------------------------------------------------------------------
__global__ __launch_bounds__(256) void fuse_rope_vmix(
    const int* __restrict__ flagp,
    __hip_bfloat16* __restrict__ q,
    __hip_bfloat16* __restrict__ k,
    __hip_bfloat16* __restrict__ v,
    const void* __restrict__ v1,
    const void* __restrict__ lambp)
{
  const int f    = *flagp;
  const int task = blockIdx.x * 4 + (threadIdx.x >> 6);
  const int lane = threadIdx.x & 63;
  const int h  = task & 15;
  const int bt = task >> 4;
  const int t  = bt & (T_ - 1);
  const size_t base = (size_t)bt * C_ + h * D_ + lane;

  const int j = lane & 31;
  const float inv = expf(-(float)j * (9.2103403719761836f / 32.0f));
  const float ang = (float)t * inv;
  const float cs = cosf(ang), sn = sinf(ang);
  const float EPS = 0.0078125f;

  {
    float xv = __bfloat162float(q[base]);
    float ss = xv * xv;
#pragma unroll
    for (int off = 32; off >= 1; off >>= 1) ss += __shfl_xor(ss, off);
    float r  = rsqrtf(ss * (1.0f / 64.0f) + EPS);
    float xn = xv * r;
    float pr = __shfl_xor(xn, 32);
    float yv = (lane < 32) ? (xn * cs + pr * sn) : (pr * -sn + xn * cs);
    q[base] = __float2bfloat16(yv);
  }
  {
    float xv = __bfloat162float(k[base]);
    float ss = xv * xv;
#pragma unroll
    for (int off = 32; off >= 1; off >>= 1) ss += __shfl_xor(ss, off);
    float r  = rsqrtf(ss * (1.0f / 64.0f) + EPS);
    float xn = xv * r;
    float pr = __shfl_xor(xn, 32);
    float yv = (lane < 32) ? (xn * cs + pr * sn) : (pr * -sn + xn * cs);
    k[base] = __float2bfloat16(yv);
  }
  {
    float lam = load1_adapt(lambp, 0, f);
    float vv  = __bfloat162float(v[base]);
    float v1v = load1_adapt(v1, base, f);
    v[base] = __float2bfloat16((1.0f - lam) * vv + lam * v1v);
  }
}

// ---------------------------------------------------------------------------
// MFMA flash attention fwd (causal). 4 waves, 128 q-rows/block (32/wave as
// two 16-row tiles), K-tile 64. T14 async-STAGE split: next K/V tile's global
// loads issue at iteration top (into regs), LDS write happens after the read
// barrier — HBM/L2 latency hides under QK+softmax+PV. Single-buffered LDS
// (30208 B -> 5 blocks/CU). Per-wave compute-skip for fully-masked s-tiles.
// Ps stride 76 (conflict-free). Heavy blocks launch first (reversed q0).
// y aliases q (block-local slice).
// ---------------------------------------------------------------------------
__global__ __launch_bounds__(256) void attn_mfma(
    const __bf16* q,
    const __bf16* __restrict__ k,
    const __bf16* __restrict__ v,
    __bf16* y)
{
  __shared__ alignas(16) __bf16 Ks[64][72];     // [s][d]
  __shared__ alignas(16) __bf16 VTs[64][88];    // [d][s]
  __shared__ alignas(16) __bf16 Ps[4][16][76];  // per-wave P [q][s], stride 76

  const int tid  = threadIdx.x;
  const int wv   = tid >> 6;
  const int lane = tid & 63;
  const int n16  = lane & 15;
  const int quad = lane >> 4;
  const int b = blockIdx.y >> 4, h = blockIdx.y & 15;
  const int q0 = (gridDim.x - 1 - blockIdx.x) * 128;   // heavy blocks first
  const size_t hb = (size_t)b * T_ * C_ + h * D_;

  // ---- Q fragments for two 16-row tiles, pre-scaled by 1/8 (exact in bf16)
  bf16x8 aq[2][2];
#pragma unroll
  for (int rt = 0; rt < 2; rt++) {
    const size_t qoff = hb + (size_t)(q0 + wv * 32 + rt * 16 + n16) * C_;
    aq[rt][0] = *(const bf16x8*)(q + qoff + quad * 8);
    aq[rt][1] = *(const bf16x8*)(q + qoff + 32 + quad * 8);
#pragma unroll
    for (int jj = 0; jj < 8; jj++) {
      aq[rt][0][jj] = (__bf16)((float)aq[rt][0][jj] * 0.125f);
      aq[rt][1][jj] = (__bf16)((float)aq[rt][1][jj] * 0.125f);
    }
  }

  f32x4 Ot[2][4];
  float m_run[2][4], l_run[2][4];
#pragma unroll
  for (int rt = 0; rt < 2; rt++)
#pragma unroll
    for (int r = 0; r < 4; r++) {
      Ot[rt][r] = (f32x4){0.f, 0.f, 0.f, 0.f};
      m_run[rt][r] = -1e30f;
      l_run[rt][r] = 0.0f;
    }

  // staging thread->slot maps
  const int trow = tid >> 2;          // K: 0..63
  const int tcol = (tid & 3) * 16;    // K: 0,16,32,48

  const int niter = q0 / 64 + 2;      // s-tiles cover 0 .. q0+127

  // ---- prologue: stage tile 0 ----
  bf16x8 kr0, kr1, vr0, vr1;
  {
    const __bf16* ks = k + hb + (size_t)trow * C_ + tcol;
    kr0 = *(const bf16x8*)(ks);
    kr1 = *(const bf16x8*)(ks + 8);
    const __bf16* vs = v + hb + (size_t)lane * C_;
    vr0 = *(const bf16x8*)(vs + wv * 8);
    vr1 = *(const bf16x8*)(vs + (wv + 4) * 8);
    *(bf16x8*)&Ks[trow][tcol]     = kr0;
    *(bf16x8*)&Ks[trow][tcol + 8] = kr1;
#pragma unroll
    for (int jj = 0; jj < 8; jj++) VTs[wv * 8 + jj][lane] = vr0[jj];
#pragma unroll
    for (int jj = 0; jj < 8; jj++) VTs[(wv + 4) * 8 + jj][lane] = vr1[jj];
  }
  __syncthreads();

  for (int it = 0; it < niter; it++) {
    const int s0 = it * 64;
    const bool havenext = (it + 1 < niter);

    // ---- issue next tile's global loads NOW (latency hides under compute)
    if (havenext) {
      const int sn = s0 + 64;
      const __bf16* ks = k + hb + (size_t)(sn + trow) * C_ + tcol;
      kr0 = *(const bf16x8*)(ks);
      kr1 = *(const bf16x8*)(ks + 8);
      const __bf16* vs = v + hb + (size_t)(sn + lane) * C_;
      vr0 = *(const bf16x8*)(vs + wv * 8);
      vr1 = *(const bf16x8*)(vs + (wv + 4) * 8);
    }

    // ---- compute current tile (skip if fully above this wave's diagonal)
    if (s0 <= q0 + wv * 32 + 31) {
#pragma unroll
      for (int rt = 0; rt < 2; rt++) {
        const int rbase = q0 + wv * 32 + rt * 16;
        if (s0 <= rbase + 15) {
          // ---- S = Q K^T ----
          f32x4 S[4];
#pragma unroll
          for (int t = 0; t < 4; t++) {
            S[t] = (f32x4){0.f, 0.f, 0.f, 0.f};
            bf16x8 b0 = *(const bf16x8*)&Ks[t * 16 + n16][quad * 8];
            bf16x8 b1 = *(const bf16x8*)&Ks[t * 16 + n16][32 + quad * 8];
            S[t] = __builtin_amdgcn_mfma_f32_16x16x32_bf16(aq[rt][0], b0, S[t], 0, 0, 0);
            S[t] = __builtin_amdgcn_mfma_f32_16x16x32_bf16(aq[rt][1], b1, S[t], 0, 0, 0);
          }

          // ---- causal mask (only when tile crosses this row-tile's diagonal)
          if (s0 + 63 > rbase) {
#pragma unroll
            for (int t = 0; t < 4; t++) {
              const int sg = s0 + t * 16 + n16;
#pragma unroll
              for (int r = 0; r < 4; r++) {
                const int tg = rbase + quad * 4 + r;
                if (sg > tg) S[t][r] = -1e30f;
              }
            }
          }

          // ---- online softmax; P -> per-wave LDS (stride 76) ----
#pragma unroll
          for (int r = 0; r < 4; r++) {
            float mx = fmaxf(fmaxf(S[0][r], S[1][r]), fmaxf(S[2][r], S[3][r]));
            mx = fmaxf(mx, __shfl_xor(mx, 1));
            mx = fmaxf(mx, __shfl_xor(mx, 2));
            mx = fmaxf(mx, __shfl_xor(mx, 4));
            mx = fmaxf(mx, __shfl_xor(mx, 8));
            const float mnew = fmaxf(m_run[rt][r], mx);
            const float al   = __expf(m_run[rt][r] - mnew);
            m_run[rt][r] = mnew;
            float p0 = __expf(S[0][r] - mnew), p1 = __expf(S[1][r] - mnew);
            float p2 = __expf(S[2][r] - mnew), p3 = __expf(S[3][r] - mnew);
            float su = p0 + p1 + p2 + p3;
            su += __shfl_xor(su, 1);
            su += __shfl_xor(su, 2);
            su += __shfl_xor(su, 4);
            su += __shfl_xor(su, 8);
            l_run[rt][r] = l_run[rt][r] * al + su;
#pragma unroll
            for (int t = 0; t < 4; t++) Ot[rt][t][r] *= al;
            const int prow = quad * 4 + r;
            Ps[wv][prow][n16]      = (__bf16)p0;
            Ps[wv][prow][16 + n16] = (__bf16)p1;
            Ps[wv][prow][32 + n16] = (__bf16)p2;
            Ps[wv][prow][48 + n16] = (__bf16)p3;
          }

          // ---- O += P V (A-frag from Ps via 2x b64; B = VT) ----
          bf16x4 l0 = *(const bf16x4*)&Ps[wv][n16][quad * 8];
          bf16x4 l1 = *(const bf16x4*)&Ps[wv][n16][quad * 8 + 4];
          bf16x4 l2 = *(const bf16x4*)&Ps[wv][n16][32 + quad * 8];
          bf16x4 l3 = *(const bf16x4*)&Ps[wv][n16][32 + quad * 8 + 4];
          bf16x8 ap0 = __builtin_shufflevector(l0, l1, 0, 1, 2, 3, 4, 5, 6, 7);
          bf16x8 ap1 = __builtin_shufflevector(l2, l3, 0, 1, 2, 3, 4, 5, 6, 7);
#pragma unroll
          for (int t = 0; t < 4; t++) {
            bf16x8 b0 = *(const bf16x8*)&VTs[t * 16 + n16][quad * 8];
            bf16x8 b1 = *(const bf16x8*)&VTs[t * 16 + n16][32 + quad * 8];
            Ot[rt][t] = __builtin_amdgcn_mfma_f32_16x16x32_bf16(ap0, b0, Ot[rt][t], 0, 0, 0);
            Ot[rt][t] = __builtin_amdgcn_mfma_f32_16x16x32_bf16(ap1, b1, Ot[rt][t], 0, 0, 0);
          }
        }
      }
    }

    __syncthreads();             // everyone done reading Ks/VTs
    if (havenext) {              // write-late: regs -> LDS (vmcnt wait is short)
      *(bf16x8*)&Ks[trow][tcol]     = kr0;
      *(bf16x8*)&Ks[trow][tcol + 8] = kr1;
#pragma unroll
      for (int jj = 0; jj < 8; jj++) VTs[wv * 8 + jj][lane] = vr0[jj];
#pragma unroll
      for (int jj = 0; jj < 8; jj++) VTs[(wv + 4) * 8 + jj][lane] = vr1[jj];
    }
    __syncthreads();             // LDS valid for next iteration
  }

  // ---- epilogue ----
#pragma unroll
  for (int rt = 0; rt < 2; rt++) {
    float linv[4];
#pragma unroll
    for (int r = 0; r < 4; r++) linv[r] = 1.0f / l_run[rt][r];
    const int orow = q0 + wv * 32 + rt * 16 + quad * 4;
#pragma unroll
    for (int t = 0; t < 4; t++)
#pragma unroll
      for (int r = 0; r < 4; r++)
        y[hb + (size_t)(orow + r) * C_ + t * 16 + n16] =
            (__bf16)(Ot[rt][t][r] * linv[r]);
  }
}

// ---------------------------------------------------------------------------
__global__ __launch_bounds__(256) void copy_v1(
    const int* __restrict__ flagp, const void* __restrict__ v1, void* __restrict__ out)
{
  const int f = *flagp;
  const size_t nbytes = NE_ * (f ? 4u : 2u);
  const uint4* s = (const uint4*)v1;
  uint4* d = (uint4*)((char*)out + nbytes);
  const size_t n16 = nbytes / 16;
  for (size_t i = (size_t)blockIdx.x * 256 + threadIdx.x; i < n16;
       i += (size_t)gridDim.x * 256)
    d[i] = s[i];
}

// ---------------------------------------------------------------------------
extern "C" void kernel_launch(void* const* d_in, const int* in_sizes, int n_in,
                              void* d_out, int out_size, void* d_ws, size_t ws_size,
                              hipStream_t stream)
{
  const void* x    = d_in[0];
  const void* v1   = d_in[1];
  const void* Wq   = d_in[2];
  const void* Wk   = d_in[3];
  const void* Wv   = d_in[4];
  const void* Wp   = d_in[5];
  const void* lamb = d_in[6];

  // ws layout (bf16): xb | qw | Wq | Wk | Wv | Wp | flag  (~42 MB)
  __bf16* xb  = (__bf16*)d_ws;
  __bf16* qw  = xb + NE_;
  __bf16* wqb = qw + NE_;
  __bf16* wkb = wqb + (size_t)C_ * C_;
  __bf16* wvb = wkb + (size_t)C_ * C_;
  __bf16* wpb = wvb + (size_t)C_ * C_;
  int* flagp  = (int*)(wpb + (size_t)C_ * C_);
  // k, v staging in d_out (safe under both dtypes; dead before final writes)
  __bf16* kw = (__bf16*)d_out;
  __bf16* vw = (__bf16*)((char*)d_out + NE_ * 2);

  probe_dtype<<<1, 256, 0, stream>>>((const unsigned short*)x, flagp);

  cvt_bf16<<<4096, 256, 0, stream>>>(flagp, x,  xb,  (int)NE_);
  cvt_bf16<<<512,  256, 0, stream>>>(flagp, Wq, wqb, C_ * C_);
  cvt_bf16<<<512,  256, 0, stream>>>(flagp, Wk, wkb, C_ * C_);
  cvt_bf16<<<512,  256, 0, stream>>>(flagp, Wv, wvb, C_ * C_);
  cvt_bf16<<<512,  256, 0, stream>>>(flagp, Wp, wpb, C_ * C_);

  dim3 gg(M_ / 128, C_ / 128);
  gemm128<<<gg, 256, 0, stream>>>(xb, wqb, qw, M_, C_, C_, flagp, 0);
  gemm128<<<gg, 256, 0, stream>>>(xb, wkb, kw, M_, C_, C_, flagp, 0);
  gemm128<<<gg, 256, 0, stream>>>(xb, wvb, vw, M_, C_, C_, flagp, 0);

  fuse_rope_vmix<<<(M_ * H_) / 4, 256, 0, stream>>>(
      flagp, (__hip_bfloat16*)qw, (__hip_bfloat16*)kw, (__hip_bfloat16*)vw,
      v1, lamb);

  attn_mfma<<<dim3(T_ / 128, B_ * H_), 256, 0, stream>>>(qw, kw, vw, qw);

  gemm128<<<gg, 256, 0, stream>>>(qw, wpb, d_out, M_, C_, C_, flagp, 1);
  copy_v1<<<8192, 256, 0, stream>>>(flagp, v1, d_out);
}

// Round 2
// 451.427 us; speedup vs baseline: 1.2017x; 1.2017x over previous
//
#include <hip/hip_runtime.h>
#include <hip/hip_bf16.h>

typedef __bf16 bf16x8 __attribute__((ext_vector_type(8)));
typedef __bf16 bf16x4 __attribute__((ext_vector_type(4)));
typedef float  f32x4  __attribute__((ext_vector_type(4)));

#define B_ 4
#define T_ 2048
#define H_ 16
#define D_ 64
#define C_ 1024
#define M_ 8192                    // B*T
#define NE_ ((size_t)M_ * C_)      // elems per (M,C) tensor

// ---------------------------------------------------------------------------
// Probe: flag=1 if inputs are fp32, flag=0 if bf16.
// ---------------------------------------------------------------------------
__global__ void probe_dtype(const unsigned short* __restrict__ x,
                            int* __restrict__ flag)
{
  __shared__ float red[256];
  float m = 0.0f;
  for (int i = threadIdx.x; i < 4096; i += 256) {
    unsigned int u = ((unsigned int)x[i]) << 16;
    float v = fabsf(__uint_as_float(u));
    if (!(v <= 1e30f)) v = 1e31f;
    m = fmaxf(m, v);
  }
  red[threadIdx.x] = m;
  __syncthreads();
  for (int s = 128; s > 0; s >>= 1) {
    if (threadIdx.x < s) red[threadIdx.x] = fmaxf(red[threadIdx.x], red[threadIdx.x + s]);
    __syncthreads();
  }
  if (threadIdx.x == 0) *flag = (red[0] > 100.0f) ? 1 : 0;
}

__device__ __forceinline__ float load1_adapt(const void* p, size_t idx, int f)
{
  if (f) return ((const float*)p)[idx];
  return __bfloat162float(((const __hip_bfloat16*)p)[idx]);
}

// ---------------------------------------------------------------------------
// Convert a tensor to bf16 (fp32 src if flag, else plain bf16 copy).
// ---------------------------------------------------------------------------
__global__ __launch_bounds__(256) void cvt_bf16(
    const int* __restrict__ flagp, const void* __restrict__ src,
    __bf16* __restrict__ dst, int n)
{
  const int f = *flagp;
  for (size_t i = ((size_t)blockIdx.x * 256 + threadIdx.x) * 8; i < (size_t)n;
       i += (size_t)gridDim.x * 2048) {
    bf16x8 r;
    if (f) {
      const float* pf = (const float*)src + i;
      float4 a = *(const float4*)pf;
      float4 b = *(const float4*)(pf + 4);
      r[0] = (__bf16)a.x; r[1] = (__bf16)a.y; r[2] = (__bf16)a.z; r[3] = (__bf16)a.w;
      r[4] = (__bf16)b.x; r[5] = (__bf16)b.y; r[6] = (__bf16)b.z; r[7] = (__bf16)b.w;
    } else {
      r = *(const bf16x8*)((const __bf16*)src + i);
    }
    *(bf16x8*)(dst + i) = r;
  }
}

// ---------------------------------------------------------------------------
// async 16B global -> LDS copy (gfx950 global_load_lds dwordx4)
// ---------------------------------------------------------------------------
__device__ __forceinline__ void g2lds16(const __bf16* g, __bf16* l)
{
  __builtin_amdgcn_global_load_lds(
      (const __attribute__((address_space(1))) void*)g,
      (__attribute__((address_space(3))) void*)l, 16, 0, 0);
}

// ---------------------------------------------------------------------------
// m97-style GEMM: C = A * Bm^T. A: MxK bf16, Bm: NxK bf16. 128x128 tile,
// BK=64, 4 waves (2x2), global_load_lds width-16 staging (unpadded LDS —
// required by the wave-uniform-base + lane*16 constraint).
// XCD-aware swizzle: nwg=512 divisible by 8.
// Output: bf16, or fp32 when (adaptive && *flagp).
// ---------------------------------------------------------------------------
__global__ __launch_bounds__(256) void gemm128(
    const __bf16* __restrict__ A, const __bf16* __restrict__ Bm,
    void* __restrict__ C, int M, int N, int K,
    const int* __restrict__ flagp, int adaptive)
{
  __shared__ __bf16 As[128][64];
  __shared__ __bf16 Bs[128][64];

  const int tid  = threadIdx.x;
  const int wv   = tid >> 6;
  const int lane = tid & 63;
  const int n16  = lane & 15;
  const int quad = lane >> 4;
  const int wm = (wv & 1) * 64, wn = (wv >> 1) * 64;

  // XCD-aware bijective swizzle (nwg % 8 == 0 for this launch: 64x8=512)
  const int nwgx = gridDim.x;
  const int id   = blockIdx.y * nwgx + blockIdx.x;
  const int cpx  = (nwgx * gridDim.y) >> 3;
  const int swz  = (id & 7) * cpx + (id >> 3);
  const int m0 = (swz % nwgx) * 128, n0 = (swz / nwgx) * 128;

  f32x4 acc[4][4];
#pragma unroll
  for (int i = 0; i < 4; i++)
#pragma unroll
    for (int j = 0; j < 4; j++) acc[i][j] = (f32x4){0.f, 0.f, 0.f, 0.f};

  const int trow = tid >> 3;          // 0..31
  const int tcol = (tid & 7) * 8;     // 0..56

  for (int k0 = 0; k0 < K; k0 += 64) {
#pragma unroll
    for (int p = 0; p < 4; p++) {
      g2lds16(A  + (size_t)(m0 + trow + p * 32) * K + k0 + tcol,
              &As[trow + p * 32][tcol]);
      g2lds16(Bm + (size_t)(n0 + trow + p * 32) * K + k0 + tcol,
              &Bs[trow + p * 32][tcol]);
    }
    __syncthreads();   // drains vmcnt(0): LDS is valid

#pragma unroll
    for (int kk = 0; kk < 2; kk++) {
      bf16x8 af[4], bf[4];
#pragma unroll
      for (int i = 0; i < 4; i++) {
        af[i] = *(const bf16x8*)&As[wm + i * 16 + n16][kk * 32 + quad * 8];
        bf[i] = *(const bf16x8*)&Bs[wn + i * 16 + n16][kk * 32 + quad * 8];
      }
#pragma unroll
      for (int i = 0; i < 4; i++)
#pragma unroll
        for (int j = 0; j < 4; j++)
          acc[i][j] = __builtin_amdgcn_mfma_f32_16x16x32_bf16(af[i], bf[j],
                                                              acc[i][j], 0, 0, 0);
    }
    __syncthreads();
  }

  const int f = adaptive ? *flagp : 0;
  const int rb = quad * 4;
#pragma unroll
  for (int i = 0; i < 4; i++)
#pragma unroll
    for (int j = 0; j < 4; j++)
#pragma unroll
      for (int r = 0; r < 4; r++) {
        const size_t idx = (size_t)(m0 + wm + i * 16 + rb + r) * N
                           + n0 + wn + j * 16 + n16;
        if (f) ((float*)C)[idx] = acc[i][j][r];
        else   ((__bf16*)C)[idx] = (__bf16)acc[i][j][r];
      }
}

// ---------------------------------------------------------------------------
// Fused rmsnorm+RoPE on q,k (bf16, in place) + v mix (bf16 in place, v1 raw).
// ---------------------------------------------------------------------------
__global__ __launch_bounds__(256) void fuse_rope_vmix(
    const int* __restrict__ flagp,
    __hip_bfloat16* __restrict__ q,
    __hip_bfloat16* __restrict__ k,
    __hip_bfloat16* __restrict__ v,
    const void* __restrict__ v1,
    const void* __restrict__ lambp)
{
  const int f    = *flagp;
  const int task = blockIdx.x * 4 + (threadIdx.x >> 6);
  const int lane = threadIdx.x & 63;
  const int h  = task & 15;
  const int bt = task >> 4;
  const int t  = bt & (T_ - 1);
  const size_t base = (size_t)bt * C_ + h * D_ + lane;

  const int j = lane & 31;
  const float inv = expf(-(float)j * (9.2103403719761836f / 32.0f));
  const float ang = (float)t * inv;
  const float cs = cosf(ang), sn = sinf(ang);
  const float EPS = 0.0078125f;

  {
    float xv = __bfloat162float(q[base]);
    float ss = xv * xv;
#pragma unroll
    for (int off = 32; off >= 1; off >>= 1) ss += __shfl_xor(ss, off);
    float r  = rsqrtf(ss * (1.0f / 64.0f) + EPS);
    float xn = xv * r;
    float pr = __shfl_xor(xn, 32);
    float yv = (lane < 32) ? (xn * cs + pr * sn) : (pr * -sn + xn * cs);
    q[base] = __float2bfloat16(yv);
  }
  {
    float xv = __bfloat162float(k[base]);
    float ss = xv * xv;
#pragma unroll
    for (int off = 32; off >= 1; off >>= 1) ss += __shfl_xor(ss, off);
    float r  = rsqrtf(ss * (1.0f / 64.0f) + EPS);
    float xn = xv * r;
    float pr = __shfl_xor(xn, 32);
    float yv = (lane < 32) ? (xn * cs + pr * sn) : (pr * -sn + xn * cs);
    k[base] = __float2bfloat16(yv);
  }
  {
    float lam = load1_adapt(lambp, 0, f);
    float vv  = __bfloat162float(v[base]);
    float v1v = load1_adapt(v1, base, f);
    v[base] = __float2bfloat16((1.0f - lam) * vv + lam * v1v);
  }
}

// ---------------------------------------------------------------------------
// MFMA flash attention fwd (causal). 4 waves, 128 q-rows/block (32/wave as
// two 16-row tiles), K-tile 64. T14 async-STAGE split (issue-early /
// write-late). FIXED-MAX softmax: rmsnorm guarantees ||q||=||k||=8 so
// S = q·k/8 ∈ [-8,8]; use max=8 → no running max, no rescale, no cross-lane
// reductions. Row-sum l computed by one extra MFMA pair against a constant
// all-ones B-fragment (broadcasts Σ_s P to every lane). Main loop is
// cross-lane-free. Ps stride 76. Heavy blocks first. y aliases q.
// ---------------------------------------------------------------------------
__global__ __launch_bounds__(256) void attn_mfma(
    const __bf16* q,
    const __bf16* __restrict__ k,
    const __bf16* __restrict__ v,
    __bf16* y)
{
  __shared__ alignas(16) __bf16 Ks[64][72];     // [s][d]
  __shared__ alignas(16) __bf16 VTs[64][88];    // [d][s]
  __shared__ alignas(16) __bf16 Ps[4][16][76];  // per-wave P [q][s], stride 76

  const int tid  = threadIdx.x;
  const int wv   = tid >> 6;
  const int lane = tid & 63;
  const int n16  = lane & 15;
  const int quad = lane >> 4;
  const int b = blockIdx.y >> 4, h = blockIdx.y & 15;
  const int q0 = (gridDim.x - 1 - blockIdx.x) * 128;   // heavy blocks first
  const size_t hb = (size_t)b * T_ * C_ + h * D_;

  const __bf16 one_ = (__bf16)1.0f;
  const bf16x8 onev = {one_, one_, one_, one_, one_, one_, one_, one_};

  // ---- Q fragments for two 16-row tiles, pre-scaled by 1/8 (exact in bf16)
  bf16x8 aq[2][2];
#pragma unroll
  for (int rt = 0; rt < 2; rt++) {
    const size_t qoff = hb + (size_t)(q0 + wv * 32 + rt * 16 + n16) * C_;
    aq[rt][0] = *(const bf16x8*)(q + qoff + quad * 8);
    aq[rt][1] = *(const bf16x8*)(q + qoff + 32 + quad * 8);
#pragma unroll
    for (int jj = 0; jj < 8; jj++) {
      aq[rt][0][jj] = (__bf16)((float)aq[rt][0][jj] * 0.125f);
      aq[rt][1][jj] = (__bf16)((float)aq[rt][1][jj] * 0.125f);
    }
  }

  f32x4 Ot[2][4];
  float l_run[2][4];
#pragma unroll
  for (int rt = 0; rt < 2; rt++)
#pragma unroll
    for (int r = 0; r < 4; r++) {
      Ot[rt][r] = (f32x4){0.f, 0.f, 0.f, 0.f};
      l_run[rt][r] = 0.0f;
    }

  // staging thread->slot maps
  const int trow = tid >> 2;          // K: 0..63
  const int tcol = (tid & 3) * 16;    // K: 0,16,32,48

  const int niter = q0 / 64 + 2;      // s-tiles cover 0 .. q0+127

  // ---- prologue: stage tile 0 ----
  bf16x8 kr0, kr1, vr0, vr1;
  {
    const __bf16* ks = k + hb + (size_t)trow * C_ + tcol;
    kr0 = *(const bf16x8*)(ks);
    kr1 = *(const bf16x8*)(ks + 8);
    const __bf16* vs = v + hb + (size_t)lane * C_;
    vr0 = *(const bf16x8*)(vs + wv * 8);
    vr1 = *(const bf16x8*)(vs + (wv + 4) * 8);
    *(bf16x8*)&Ks[trow][tcol]     = kr0;
    *(bf16x8*)&Ks[trow][tcol + 8] = kr1;
#pragma unroll
    for (int jj = 0; jj < 8; jj++) VTs[wv * 8 + jj][lane] = vr0[jj];
#pragma unroll
    for (int jj = 0; jj < 8; jj++) VTs[(wv + 4) * 8 + jj][lane] = vr1[jj];
  }
  __syncthreads();

  for (int it = 0; it < niter; it++) {
    const int s0 = it * 64;
    const bool havenext = (it + 1 < niter);

    // ---- issue next tile's global loads NOW (latency hides under compute)
    if (havenext) {
      const int sn = s0 + 64;
      const __bf16* ks = k + hb + (size_t)(sn + trow) * C_ + tcol;
      kr0 = *(const bf16x8*)(ks);
      kr1 = *(const bf16x8*)(ks + 8);
      const __bf16* vs = v + hb + (size_t)(sn + lane) * C_;
      vr0 = *(const bf16x8*)(vs + wv * 8);
      vr1 = *(const bf16x8*)(vs + (wv + 4) * 8);
    }

    // ---- compute current tile (skip if fully above this wave's diagonal)
    if (s0 <= q0 + wv * 32 + 31) {
#pragma unroll
      for (int rt = 0; rt < 2; rt++) {
        const int rbase = q0 + wv * 32 + rt * 16;
        if (s0 <= rbase + 15) {
          // ---- S = Q K^T ----
          f32x4 S[4];
#pragma unroll
          for (int t = 0; t < 4; t++) {
            S[t] = (f32x4){0.f, 0.f, 0.f, 0.f};
            bf16x8 b0 = *(const bf16x8*)&Ks[t * 16 + n16][quad * 8];
            bf16x8 b1 = *(const bf16x8*)&Ks[t * 16 + n16][32 + quad * 8];
            S[t] = __builtin_amdgcn_mfma_f32_16x16x32_bf16(aq[rt][0], b0, S[t], 0, 0, 0);
            S[t] = __builtin_amdgcn_mfma_f32_16x16x32_bf16(aq[rt][1], b1, S[t], 0, 0, 0);
          }

          // ---- causal mask (only when tile crosses this row-tile's diagonal)
          if (s0 + 63 > rbase) {
#pragma unroll
            for (int t = 0; t < 4; t++) {
              const int sg = s0 + t * 16 + n16;
#pragma unroll
              for (int r = 0; r < 4; r++) {
                const int tg = rbase + quad * 4 + r;
                if (sg > tg) S[t][r] = -1e30f;
              }
            }
          }

          // ---- fixed-max softmax: P = exp(S - 8), no cross-lane ops ----
#pragma unroll
          for (int r = 0; r < 4; r++) {
            float p0 = __expf(S[0][r] - 8.0f), p1 = __expf(S[1][r] - 8.0f);
            float p2 = __expf(S[2][r] - 8.0f), p3 = __expf(S[3][r] - 8.0f);
            const int prow = quad * 4 + r;
            Ps[wv][prow][n16]      = (__bf16)p0;
            Ps[wv][prow][16 + n16] = (__bf16)p1;
            Ps[wv][prow][32 + n16] = (__bf16)p2;
            Ps[wv][prow][48 + n16] = (__bf16)p3;
          }

          // ---- O += P V ; l += P @ ones (extra MFMA pair, reg-constant B)
          bf16x4 l0 = *(const bf16x4*)&Ps[wv][n16][quad * 8];
          bf16x4 l1 = *(const bf16x4*)&Ps[wv][n16][quad * 8 + 4];
          bf16x4 l2 = *(const bf16x4*)&Ps[wv][n16][32 + quad * 8];
          bf16x4 l3 = *(const bf16x4*)&Ps[wv][n16][32 + quad * 8 + 4];
          bf16x8 ap0 = __builtin_shufflevector(l0, l1, 0, 1, 2, 3, 4, 5, 6, 7);
          bf16x8 ap1 = __builtin_shufflevector(l2, l3, 0, 1, 2, 3, 4, 5, 6, 7);
#pragma unroll
          for (int t = 0; t < 4; t++) {
            bf16x8 b0 = *(const bf16x8*)&VTs[t * 16 + n16][quad * 8];
            bf16x8 b1 = *(const bf16x8*)&VTs[t * 16 + n16][32 + quad * 8];
            Ot[rt][t] = __builtin_amdgcn_mfma_f32_16x16x32_bf16(ap0, b0, Ot[rt][t], 0, 0, 0);
            Ot[rt][t] = __builtin_amdgcn_mfma_f32_16x16x32_bf16(ap1, b1, Ot[rt][t], 0, 0, 0);
          }
          f32x4 l4 = (f32x4){0.f, 0.f, 0.f, 0.f};
          l4 = __builtin_amdgcn_mfma_f32_16x16x32_bf16(ap0, onev, l4, 0, 0, 0);
          l4 = __builtin_amdgcn_mfma_f32_16x16x32_bf16(ap1, onev, l4, 0, 0, 0);
#pragma unroll
          for (int r = 0; r < 4; r++) l_run[rt][r] += l4[r];
        }
      }
    }

    __syncthreads();             // everyone done reading Ks/VTs
    if (havenext) {              // write-late: regs -> LDS (vmcnt wait is short)
      *(bf16x8*)&Ks[trow][tcol]     = kr0;
      *(bf16x8*)&Ks[trow][tcol + 8] = kr1;
#pragma unroll
      for (int jj = 0; jj < 8; jj++) VTs[wv * 8 + jj][lane] = vr0[jj];
#pragma unroll
      for (int jj = 0; jj < 8; jj++) VTs[(wv + 4) * 8 + jj][lane] = vr1[jj];
    }
    __syncthreads();             // LDS valid for next iteration
  }

  // ---- epilogue ----
#pragma unroll
  for (int rt = 0; rt < 2; rt++) {
    float linv[4];
#pragma unroll
    for (int r = 0; r < 4; r++) linv[r] = 1.0f / l_run[rt][r];
    const int orow = q0 + wv * 32 + rt * 16 + quad * 4;
#pragma unroll
    for (int t = 0; t < 4; t++)
#pragma unroll
      for (int r = 0; r < 4; r++)
        y[hb + (size_t)(orow + r) * C_ + t * 16 + n16] =
            (__bf16)(Ot[rt][t][r] * linv[r]);
  }
}

// ---------------------------------------------------------------------------
__global__ __launch_bounds__(256) void copy_v1(
    const int* __restrict__ flagp, const void* __restrict__ v1, void* __restrict__ out)
{
  const int f = *flagp;
  const size_t nbytes = NE_ * (f ? 4u : 2u);
  const uint4* s = (const uint4*)v1;
  uint4* d = (uint4*)((char*)out + nbytes);
  const size_t n16 = nbytes / 16;
  for (size_t i = (size_t)blockIdx.x * 256 + threadIdx.x; i < n16;
       i += (size_t)gridDim.x * 256)
    d[i] = s[i];
}

// ---------------------------------------------------------------------------
extern "C" void kernel_launch(void* const* d_in, const int* in_sizes, int n_in,
                              void* d_out, int out_size, void* d_ws, size_t ws_size,
                              hipStream_t stream)
{
  const void* x    = d_in[0];
  const void* v1   = d_in[1];
  const void* Wq   = d_in[2];
  const void* Wk   = d_in[3];
  const void* Wv   = d_in[4];
  const void* Wp   = d_in[5];
  const void* lamb = d_in[6];

  // ws layout (bf16): xb | qw | Wq | Wk | Wv | Wp | flag  (~42 MB)
  __bf16* xb  = (__bf16*)d_ws;
  __bf16* qw  = xb + NE_;
  __bf16* wqb = qw + NE_;
  __bf16* wkb = wqb + (size_t)C_ * C_;
  __bf16* wvb = wkb + (size_t)C_ * C_;
  __bf16* wpb = wvb + (size_t)C_ * C_;
  int* flagp  = (int*)(wpb + (size_t)C_ * C_);
  // k, v staging in d_out (safe under both dtypes; dead before final writes)
  __bf16* kw = (__bf16*)d_out;
  __bf16* vw = (__bf16*)((char*)d_out + NE_ * 2);

  probe_dtype<<<1, 256, 0, stream>>>((const unsigned short*)x, flagp);

  cvt_bf16<<<4096, 256, 0, stream>>>(flagp, x,  xb,  (int)NE_);
  cvt_bf16<<<512,  256, 0, stream>>>(flagp, Wq, wqb, C_ * C_);
  cvt_bf16<<<512,  256, 0, stream>>>(flagp, Wk, wkb, C_ * C_);
  cvt_bf16<<<512,  256, 0, stream>>>(flagp, Wv, wvb, C_ * C_);
  cvt_bf16<<<512,  256, 0, stream>>>(flagp, Wp, wpb, C_ * C_);

  dim3 gg(M_ / 128, C_ / 128);
  gemm128<<<gg, 256, 0, stream>>>(xb, wqb, qw, M_, C_, C_, flagp, 0);
  gemm128<<<gg, 256, 0, stream>>>(xb, wkb, kw, M_, C_, C_, flagp, 0);
  gemm128<<<gg, 256, 0, stream>>>(xb, wvb, vw, M_, C_, C_, flagp, 0);

  fuse_rope_vmix<<<(M_ * H_) / 4, 256, 0, stream>>>(
      flagp, (__hip_bfloat16*)qw, (__hip_bfloat16*)kw, (__hip_bfloat16*)vw,
      v1, lamb);

  attn_mfma<<<dim3(T_ / 128, B_ * H_), 256, 0, stream>>>(qw, kw, vw, qw);

  gemm128<<<gg, 256, 0, stream>>>(qw, wpb, d_out, M_, C_, C_, flagp, 1);
  copy_v1<<<8192, 256, 0, stream>>>(flagp, v1, d_out);
}